// Round 10
// baseline (86.498 us; speedup 1.0000x reference)
//
#include <hip/hip_runtime.h>

// Causal linear attention (elu+1 feature map), chunked-scan formulation.
// Shapes fixed by the reference: N=2, L=2048, H=8, D=64, M=64, fp32.
//
// R10: 2 kernels. k_chunksum (bf16 MFMA) writes per-chunk S^T aggregates
// (bf16, [m][d]) + ksum (fp32). k_out fuses the exclusive prefix-scan:
// each block accumulates its g predecessor aggregates in fp32 registers
// (coalesced uint4 reads, L2/L3-resident, zero extra LDS -> occupancy
// stays 4 blocks/CU, unlike R3's failed fusion) then runs the bf16-MFMA
// output phase. Deletes the k_scan kernel + one launch gap.

namespace {
constexpr int N_ = 2, L_ = 2048, H_ = 8, D_ = 64, M_ = 64;
constexpr int C  = 64;            // chunk length
constexpr int G  = L_ / C;        // 32 chunks per sequence
constexpr int NH = N_ * H_;       // 16 independent (n,h) sequences
constexpr int LDH = H_ * D_;      // stride (floats) between consecutive l
constexpr int TS  = 72;           // bf16 LDS row stride
constexpr float EPS_ = 1e-6f;
}

typedef __attribute__((ext_vector_type(8))) short short8;
typedef __attribute__((ext_vector_type(4))) float f32x4;

__device__ __forceinline__ float phi(float x) {
    return x > 0.0f ? x + 1.0f : __expf(x);
}
__device__ __forceinline__ unsigned short f2bf(float x) {
    unsigned int u = __float_as_uint(x);
    u += 0x7fffu + ((u >> 16) & 1u);          // round-to-nearest-even
    return (unsigned short)(u >> 16);
}
__device__ __forceinline__ float bf2f(unsigned short h) {
    return __uint_as_float(((unsigned int)h) << 16);
}

// ---------------------------------------------------------------------------
// Kernel 1 (MFMA): S_chunk^T[m][d] (bf16, packed) and ksum[d] (fp32)
// ---------------------------------------------------------------------------
__global__ __launch_bounds__(256, 4) void k_chunksum(
    const float* __restrict__ keys, const float* __restrict__ values,
    unsigned short* __restrict__ wsSb, float* __restrict__ wsK)
{
    __shared__ __align__(16) unsigned short Kt[C * TS];
    __shared__ __align__(16) unsigned short Vt[C * TS];
    const int bid = blockIdx.x;
    const int g = bid % G, nh = bid / G;
    const int n = nh / H_, h = nh % H_;
    const int t = threadIdx.x;
    const size_t base = ((size_t)(n * L_ + g * C) * H_ + h) * D_;

    // stage with transpose scatter: Kt[d][j] = phi(K)^T, Vt[m][j] = V^T
#pragma unroll
    for (int r = 0; r < 4; ++r) {
        const int f = t + 256 * r;
        const int j = f >> 4, c = (f & 15) * 4;
        const size_t ga = base + (size_t)j * LDH + c;
        const float4 kv = *(const float4*)(keys + ga);
        const float4 vv = *(const float4*)(values + ga);
        Kt[(c + 0) * TS + j] = f2bf(phi(kv.x));
        Kt[(c + 1) * TS + j] = f2bf(phi(kv.y));
        Kt[(c + 2) * TS + j] = f2bf(phi(kv.z));
        Kt[(c + 3) * TS + j] = f2bf(phi(kv.w));
        Vt[(c + 0) * TS + j] = f2bf(vv.x);
        Vt[(c + 1) * TS + j] = f2bf(vv.y);
        Vt[(c + 2) * TS + j] = f2bf(vv.z);
        Vt[(c + 3) * TS + j] = f2bf(vv.w);
    }
    __syncthreads();

    const int w = t >> 6, lane = t & 63;
    const int row16 = lane & 15, quad = lane >> 4;

    f32x4 acc[4] = {f32x4{0,0,0,0}, f32x4{0,0,0,0}, f32x4{0,0,0,0}, f32x4{0,0,0,0}};
    f32x4 accK = f32x4{0,0,0,0};
    short8 ones;
#pragma unroll
    for (int i = 0; i < 8; ++i) ones[i] = (short)0x3F80;   // bf16(1.0)

#pragma unroll
    for (int kt = 0; kt < 2; ++kt) {
        const short8 a = *(const short8*)&Kt[(16 * w + row16) * TS + quad * 8 + 32 * kt];
#pragma unroll
        for (int c = 0; c < 4; ++c) {
            const short8 b = *(const short8*)&Vt[(16 * c + row16) * TS + quad * 8 + 32 * kt];
            acc[c] = __builtin_amdgcn_mfma_f32_16x16x32_bf16(a, b, acc[c], 0, 0, 0);
        }
        accK = __builtin_amdgcn_mfma_f32_16x16x32_bf16(a, ones, accK, 0, 0, 0);
    }

    // store transposed: S^T[m][d], d-run of 4 packed into one 8B write
    unsigned short* Sc = wsSb + (size_t)bid * (D_ * M_);
#pragma unroll
    for (int c = 0; c < 4; ++c) {
        ushort4 pk;
        pk.x = f2bf(acc[c][0]); pk.y = f2bf(acc[c][1]);
        pk.z = f2bf(acc[c][2]); pk.w = f2bf(acc[c][3]);
        *(ushort4*)(Sc + (16 * c + row16) * D_ + 16 * w + quad * 4) = pk;
    }

    if (row16 == 0) {
#pragma unroll
        for (int r = 0; r < 4; ++r)
            wsK[(size_t)bid * D_ + 16 * w + quad * 4 + r] = accK[r];
    }
}

// ---------------------------------------------------------------------------
// Kernel 2 (MFMA, fused prefix): block (nh,g) sums aggregates of chunks <g
// in fp32 registers -> St (bf16 LDS); then A = tril(phiQ phiK^T);
// Z = 1/(phiQ.kp + rowsum(A) + eps); out = (A @ V + phiQ @ Sp) * Z.
// ---------------------------------------------------------------------------
__global__ __launch_bounds__(256, 4) void k_out(
    const float* __restrict__ queries, const float* __restrict__ keys,
    const float* __restrict__ values, float* __restrict__ out,
    const unsigned short* __restrict__ wsSb, const float* __restrict__ wsK)
{
    __shared__ __align__(16) unsigned short Qb[C * TS];
    __shared__ __align__(16) unsigned short Kb[C * TS];   // phi(K) -> A
    __shared__ __align__(16) unsigned short Vt[C * TS];
    __shared__ __align__(16) unsigned short St[C * TS];
    __shared__ float Rs[C];
    __shared__ float Zs[C];

    const int bid = blockIdx.x;
    const int g = bid % G, nh = bid / G;
    const int n = nh / H_, h = nh % H_;
    const int t = threadIdx.x;
    const size_t base = ((size_t)(n * L_ + g * C) * H_ + h) * D_;

    // ---- fused exclusive prefix over predecessor chunk aggregates ---------
    // S: thread t owns linear elements [16t, 16t+16) of the 4096-elem S^T
    //    (= row m0s = t>>2, cols d0s..d0s+15 with d0s = (t&3)*16).
    float ps[16] = {0.f,0.f,0.f,0.f,0.f,0.f,0.f,0.f,
                    0.f,0.f,0.f,0.f,0.f,0.f,0.f,0.f};
    float kp = 0.f;                               // kprefix[t] for t<64
    {
        const unsigned short* Sb = wsSb + (size_t)nh * G * (D_ * M_) + t * 16;
        const float* Kbase = wsK + (size_t)nh * G * D_ + (t & 63);
        // unroll-2: keeps 4 x uint4 loads in flight
        int gp = 0;
        for (; gp + 2 <= g; gp += 2) {
            const uint4 u0 = *(const uint4*)(Sb + (size_t)(gp    ) * (D_ * M_));
            const uint4 u1 = *(const uint4*)(Sb + (size_t)(gp    ) * (D_ * M_) + 8);
            const uint4 u2 = *(const uint4*)(Sb + (size_t)(gp + 1) * (D_ * M_));
            const uint4 u3 = *(const uint4*)(Sb + (size_t)(gp + 1) * (D_ * M_) + 8);
            const float k0 = Kbase[(size_t)(gp) * D_];
            const float k1 = Kbase[(size_t)(gp + 1) * D_];
            const unsigned int w0[4] = {u0.x, u0.y, u0.z, u0.w};
            const unsigned int w1[4] = {u1.x, u1.y, u1.z, u1.w};
            const unsigned int w2[4] = {u2.x, u2.y, u2.z, u2.w};
            const unsigned int w3[4] = {u3.x, u3.y, u3.z, u3.w};
#pragma unroll
            for (int i = 0; i < 4; ++i) {
                ps[2*i]   += bf2f((unsigned short)(w0[i] & 0xffffu))
                           + bf2f((unsigned short)(w2[i] & 0xffffu));
                ps[2*i+1] += bf2f((unsigned short)(w0[i] >> 16))
                           + bf2f((unsigned short)(w2[i] >> 16));
                ps[8+2*i]   += bf2f((unsigned short)(w1[i] & 0xffffu))
                             + bf2f((unsigned short)(w3[i] & 0xffffu));
                ps[8+2*i+1] += bf2f((unsigned short)(w1[i] >> 16))
                             + bf2f((unsigned short)(w3[i] >> 16));
            }
            kp += k0 + k1;
        }
        if (gp < g) {
            const uint4 u0 = *(const uint4*)(Sb + (size_t)gp * (D_ * M_));
            const uint4 u1 = *(const uint4*)(Sb + (size_t)gp * (D_ * M_) + 8);
            const unsigned int w0[4] = {u0.x, u0.y, u0.z, u0.w};
            const unsigned int w1[4] = {u1.x, u1.y, u1.z, u1.w};
#pragma unroll
            for (int i = 0; i < 4; ++i) {
                ps[2*i]     += bf2f((unsigned short)(w0[i] & 0xffffu));
                ps[2*i+1]   += bf2f((unsigned short)(w0[i] >> 16));
                ps[8+2*i]   += bf2f((unsigned short)(w1[i] & 0xffffu));
                ps[8+2*i+1] += bf2f((unsigned short)(w1[i] >> 16));
            }
            kp += Kbase[(size_t)gp * D_];
        }
    }

    // ---- stage: Qb/Kb contiguous, Vt transposed, St from prefix regs ------
#pragma unroll
    for (int r = 0; r < 4; ++r) {
        const int f = t + 256 * r;
        const int row = f >> 4, c = (f & 15) * 4;
        const size_t ga = base + (size_t)row * LDH + c;
        const float4 qv = *(const float4*)(queries + ga);
        const float4 kv = *(const float4*)(keys + ga);
        const float4 vv = *(const float4*)(values + ga);
        Qb[row * TS + c + 0] = f2bf(phi(qv.x));
        Qb[row * TS + c + 1] = f2bf(phi(qv.y));
        Qb[row * TS + c + 2] = f2bf(phi(qv.z));
        Qb[row * TS + c + 3] = f2bf(phi(qv.w));
        Kb[row * TS + c + 0] = f2bf(phi(kv.x));
        Kb[row * TS + c + 1] = f2bf(phi(kv.y));
        Kb[row * TS + c + 2] = f2bf(phi(kv.z));
        Kb[row * TS + c + 3] = f2bf(phi(kv.w));
        Vt[(c + 0) * TS + row] = f2bf(vv.x);
        Vt[(c + 1) * TS + row] = f2bf(vv.y);
        Vt[(c + 2) * TS + row] = f2bf(vv.z);
        Vt[(c + 3) * TS + row] = f2bf(vv.w);
    }
    {
        const int m0s = t >> 2, d0s = (t & 3) * 16;
        short8 p0, p1;
#pragma unroll
        for (int i = 0; i < 8; ++i) { p0[i] = (short)f2bf(ps[i]); p1[i] = (short)f2bf(ps[8 + i]); }
        *(short8*)&St[m0s * TS + d0s]     = p0;
        *(short8*)&St[m0s * TS + d0s + 8] = p1;
    }
    __syncthreads();

    const int w = t >> 6, lane = t & 63;
    const int row16 = lane & 15, quad = lane >> 4;

    // ---- QK^T: wave w -> rows 16w..16w+15, all 4 col-tiles ----------------
    short8 aq[2];
#pragma unroll
    for (int kt = 0; kt < 2; ++kt)
        aq[kt] = *(const short8*)&Qb[(16 * w + row16) * TS + quad * 8 + 32 * kt];

    f32x4 accA[4] = {f32x4{0,0,0,0}, f32x4{0,0,0,0}, f32x4{0,0,0,0}, f32x4{0,0,0,0}};
#pragma unroll
    for (int kt = 0; kt < 2; ++kt)
#pragma unroll
        for (int c = 0; c < 4; ++c) {
            const short8 b = *(const short8*)&Kb[(16 * c + row16) * TS + quad * 8 + 32 * kt];
            accA[c] = __builtin_amdgcn_mfma_f32_16x16x32_bf16(aq[kt], b, accA[c], 0, 0, 0);
        }

    // ---- mask (causal) in fp32 + rowsums ----------------------------------
    float rs[4] = {0.f, 0.f, 0.f, 0.f};
#pragma unroll
    for (int c = 0; c < 4; ++c)
#pragma unroll
        for (int r = 0; r < 4; ++r) {
            const int row = 16 * w + quad * 4 + r;
            const int col = 16 * c + row16;
            const float v = (col <= row) ? accA[c][r] : 0.f;
            accA[c][r] = v;
            rs[r] += v;
        }
#pragma unroll
    for (int off = 1; off < 16; off <<= 1)
#pragma unroll
        for (int r = 0; r < 4; ++r)
            rs[r] += __shfl_xor(rs[r], off, 64);
    if (row16 == 0) {
#pragma unroll
        for (int r = 0; r < 4; ++r)
            Rs[16 * w + quad * 4 + r] = rs[r];
    }
    __syncthreads();   // all Kb reads done; Rs complete

    // ---- write A (bf16) into Kb slab; compute Z ---------------------------
#pragma unroll
    for (int c = 0; c < 4; ++c)
#pragma unroll
        for (int r = 0; r < 4; ++r)
            Kb[(16 * w + quad * 4 + r) * TS + 16 * c + row16] = f2bf(accA[c][r]);

    if (t < C) {
        float zd = 0.f;
#pragma unroll 8
        for (int d = 0; d < D_; ++d)
            zd += bf2f(Qb[t * TS + d]) * __shfl(kp, d, 64);
        // __shfl over 64 lanes: kp holds kprefix[t&63]; for t<64 lane d gives kprefix[d]
        Zs[t] = 1.0f / (zd + Rs[t] + EPS_);
    }
    __syncthreads();   // Ab + Zs ready

    // ---- out = (A @ V + Q @ Sp) * Z ---------------------------------------
    f32x4 accO[4] = {f32x4{0,0,0,0}, f32x4{0,0,0,0}, f32x4{0,0,0,0}, f32x4{0,0,0,0}};
#pragma unroll
    for (int kt = 0; kt < 2; ++kt) {
        const short8 aA = *(const short8*)&Kb[(16 * w + row16) * TS + quad * 8 + 32 * kt];
#pragma unroll
        for (int c = 0; c < 4; ++c) {
            const short8 bV = *(const short8*)&Vt[(16 * c + row16) * TS + quad * 8 + 32 * kt];
            accO[c] = __builtin_amdgcn_mfma_f32_16x16x32_bf16(aA, bV, accO[c], 0, 0, 0);
        }
#pragma unroll
        for (int c = 0; c < 4; ++c) {
            const short8 bS = *(const short8*)&St[(16 * c + row16) * TS + quad * 8 + 32 * kt];
            accO[c] = __builtin_amdgcn_mfma_f32_16x16x32_bf16(aq[kt], bS, accO[c], 0, 0, 0);
        }
    }

#pragma unroll
    for (int r = 0; r < 4; ++r) {
        const int row = 16 * w + quad * 4 + r;
        const float z = Zs[row];
        const size_t ob = ((size_t)(n * L_ + g * C + row) * H_ + h) * M_;
#pragma unroll
        for (int c = 0; c < 4; ++c)
            out[ob + 16 * c + row16] = accO[c][r] * z;
    }
}

extern "C" void kernel_launch(void* const* d_in, const int* in_sizes, int n_in,
                              void* d_out, int out_size, void* d_ws, size_t ws_size,
                              hipStream_t stream) {
    const float* q = (const float*)d_in[0];
    const float* k = (const float*)d_in[1];
    const float* v = (const float*)d_in[2];
    float* out = (float*)d_out;
    unsigned short* wsSb = (unsigned short*)d_ws;            // NH*G*D*M bf16 (4 MB)
    float* wsK = (float*)((char*)d_ws + (size_t)NH * G * D_ * M_ * 2);  // fp32 128 KB

    k_chunksum<<<dim3(NH * G), dim3(256), 0, stream>>>(k, v, wsSb, wsK);
    k_out<<<dim3(NH * G), dim3(256), 0, stream>>>(q, k, v, out, wsSb, wsK);
}

// Round 11
// 83.806 us; speedup vs baseline: 1.0321x; 1.0321x over previous
//
#include <hip/hip_runtime.h>

// Causal linear attention (elu+1 feature map), chunked-scan formulation.
// Shapes fixed by the reference: N=2, L=2048, H=8, D=64, M=64, fp32.
//
// R11: revert to R9 (best measured: 84.7us; R10's fused prefix regressed —
// tail-block serial prefix reads beat the saved launch) + packed ushort4
// LDS staging stores for Qb/Kb in k_out (1 x 8B store vs 4 scalar stores).
// Structure: k_chunksum (bf16 MFMA, bf16 S^T aggregates) -> k_scan (parallel
// exclusive prefix, packed bf16 pairs) -> k_out (bf16 MFMA output phase).

namespace {
constexpr int N_ = 2, L_ = 2048, H_ = 8, D_ = 64, M_ = 64;
constexpr int C  = 64;            // chunk length
constexpr int G  = L_ / C;        // 32 chunks per sequence
constexpr int NH = N_ * H_;       // 16 independent (n,h) sequences
constexpr int LDH = H_ * D_;      // stride (floats) between consecutive l
constexpr int TS  = 72;           // bf16 LDS row stride
constexpr float EPS_ = 1e-6f;
}

typedef __attribute__((ext_vector_type(8))) short short8;
typedef __attribute__((ext_vector_type(4))) float f32x4;

__device__ __forceinline__ float phi(float x) {
    return x > 0.0f ? x + 1.0f : __expf(x);
}
__device__ __forceinline__ unsigned short f2bf(float x) {
    unsigned int u = __float_as_uint(x);
    u += 0x7fffu + ((u >> 16) & 1u);          // round-to-nearest-even
    return (unsigned short)(u >> 16);
}
__device__ __forceinline__ float bf2f(unsigned short h) {
    return __uint_as_float(((unsigned int)h) << 16);
}
__device__ __forceinline__ ushort4 pack4(float a, float b, float c, float d) {
    ushort4 p; p.x = f2bf(a); p.y = f2bf(b); p.z = f2bf(c); p.w = f2bf(d);
    return p;
}

// ---------------------------------------------------------------------------
// Kernel 1 (MFMA): S_chunk^T[m][d] (bf16, packed) and ksum[d] (fp32)
// ---------------------------------------------------------------------------
__global__ __launch_bounds__(256, 4) void k_chunksum(
    const float* __restrict__ keys, const float* __restrict__ values,
    unsigned short* __restrict__ wsSb, float* __restrict__ wsK)
{
    __shared__ __align__(16) unsigned short Kt[C * TS];
    __shared__ __align__(16) unsigned short Vt[C * TS];
    const int bid = blockIdx.x;
    const int g = bid % G, nh = bid / G;
    const int n = nh / H_, h = nh % H_;
    const int t = threadIdx.x;
    const size_t base = ((size_t)(n * L_ + g * C) * H_ + h) * D_;

    // stage with transpose scatter: Kt[d][j] = phi(K)^T, Vt[m][j] = V^T
#pragma unroll
    for (int r = 0; r < 4; ++r) {
        const int f = t + 256 * r;
        const int j = f >> 4, c = (f & 15) * 4;
        const size_t ga = base + (size_t)j * LDH + c;
        const float4 kv = *(const float4*)(keys + ga);
        const float4 vv = *(const float4*)(values + ga);
        Kt[(c + 0) * TS + j] = f2bf(phi(kv.x));
        Kt[(c + 1) * TS + j] = f2bf(phi(kv.y));
        Kt[(c + 2) * TS + j] = f2bf(phi(kv.z));
        Kt[(c + 3) * TS + j] = f2bf(phi(kv.w));
        Vt[(c + 0) * TS + j] = f2bf(vv.x);
        Vt[(c + 1) * TS + j] = f2bf(vv.y);
        Vt[(c + 2) * TS + j] = f2bf(vv.z);
        Vt[(c + 3) * TS + j] = f2bf(vv.w);
    }
    __syncthreads();

    const int w = t >> 6, lane = t & 63;
    const int row16 = lane & 15, quad = lane >> 4;

    f32x4 acc[4] = {f32x4{0,0,0,0}, f32x4{0,0,0,0}, f32x4{0,0,0,0}, f32x4{0,0,0,0}};
    f32x4 accK = f32x4{0,0,0,0};
    short8 ones;
#pragma unroll
    for (int i = 0; i < 8; ++i) ones[i] = (short)0x3F80;   // bf16(1.0)

#pragma unroll
    for (int kt = 0; kt < 2; ++kt) {
        const short8 a = *(const short8*)&Kt[(16 * w + row16) * TS + quad * 8 + 32 * kt];
#pragma unroll
        for (int c = 0; c < 4; ++c) {
            const short8 b = *(const short8*)&Vt[(16 * c + row16) * TS + quad * 8 + 32 * kt];
            acc[c] = __builtin_amdgcn_mfma_f32_16x16x32_bf16(a, b, acc[c], 0, 0, 0);
        }
        accK = __builtin_amdgcn_mfma_f32_16x16x32_bf16(a, ones, accK, 0, 0, 0);
    }

    // store transposed: S^T[m][d], d-run of 4 packed into one 8B write
    unsigned short* Sc = wsSb + (size_t)bid * (D_ * M_);
#pragma unroll
    for (int c = 0; c < 4; ++c) {
        *(ushort4*)(Sc + (16 * c + row16) * D_ + 16 * w + quad * 4) =
            pack4(acc[c][0], acc[c][1], acc[c][2], acc[c][3]);
    }

    if (row16 == 0) {
#pragma unroll
        for (int r = 0; r < 4; ++r)
            wsK[(size_t)bid * D_ + 16 * w + quad * 4 + r] = accK[r];
    }
}

// ---------------------------------------------------------------------------
// Kernel 2: exclusive prefix scan over chunks.
// S: bf16, 2 chains packed per uint per thread (fp32 running sums).
// ksum: fp32, one float per thread (blocks with q==0).
// ---------------------------------------------------------------------------
__global__ __launch_bounds__(256) void k_scan(
    unsigned short* __restrict__ wsSb, float* __restrict__ wsK)
{
    const int bid = blockIdx.x;               // 128 blocks
    const int nh = bid >> 3, q = bid & 7;     // 8 blocks per nh
    const int t = threadIdx.x;

    unsigned int* base =
        (unsigned int*)(wsSb + (size_t)nh * G * (D_ * M_) + q * 512 + t * 2);
    float r0 = 0.f, r1 = 0.f;
#pragma unroll
    for (int g = 0; g < G; ++g) {
        unsigned int* p = base + (size_t)g * (D_ * M_ / 2);
        const unsigned int v = *p;
        const float v0 = bf2f((unsigned short)(v & 0xffffu));
        const float v1 = bf2f((unsigned short)(v >> 16));
        *p = ((unsigned int)f2bf(r1) << 16) | (unsigned int)f2bf(r0);
        r0 += v0; r1 += v1;
    }

    if (q == 0 && t < D_) {
        float rk = 0.f;
        float* kb = wsK + (size_t)nh * G * D_ + t;
#pragma unroll
        for (int g = 0; g < G; ++g) {
            float* p = kb + (size_t)g * D_;
            const float v = *p;
            *p = rk;
            rk += v;
        }
    }
}

// ---------------------------------------------------------------------------
// Kernel 3 (MFMA): A = tril(phiQ phiK^T); Z = 1/(phiQ.kp + rowsum(A) + eps);
// out = (A @ V + phiQ @ Sp) * Z.
// Qb/Kb row-major bf16 (packed ushort4 stores); Vt transposed (scatter);
// St^T copied straight from ws (bf16, pre-transposed).
// ---------------------------------------------------------------------------
__global__ __launch_bounds__(256, 4) void k_out(
    const float* __restrict__ queries, const float* __restrict__ keys,
    const float* __restrict__ values, float* __restrict__ out,
    const unsigned short* __restrict__ wsSb, const float* __restrict__ wsK)
{
    __shared__ __align__(16) unsigned short Qb[C * TS];
    __shared__ __align__(16) unsigned short Kb[C * TS];   // phi(K) -> A
    __shared__ __align__(16) unsigned short Vt[C * TS];
    __shared__ __align__(16) unsigned short St[C * TS];
    __shared__ float Rs[C];
    __shared__ float Zs[C];

    const int bid = blockIdx.x;
    const int g = bid % G, nh = bid / G;
    const int n = nh / H_, h = nh % H_;
    const int t = threadIdx.x;
    const size_t base = ((size_t)(n * L_ + g * C) * H_ + h) * D_;
    const unsigned short* Spb = wsSb + (size_t)bid * (D_ * M_);
    const float* kpref = wsK + (size_t)bid * D_;

    // ---- stage: Qb/Kb contiguous (packed stores), Vt transposed -----------
#pragma unroll
    for (int r = 0; r < 4; ++r) {
        const int f = t + 256 * r;
        const int row = f >> 4, c = (f & 15) * 4;
        const size_t ga = base + (size_t)row * LDH + c;
        const float4 qv = *(const float4*)(queries + ga);
        const float4 kv = *(const float4*)(keys + ga);
        const float4 vv = *(const float4*)(values + ga);
        *(ushort4*)&Qb[row * TS + c] = pack4(phi(qv.x), phi(qv.y), phi(qv.z), phi(qv.w));
        *(ushort4*)&Kb[row * TS + c] = pack4(phi(kv.x), phi(kv.y), phi(kv.z), phi(kv.w));
        Vt[(c + 0) * TS + row] = f2bf(vv.x);
        Vt[(c + 1) * TS + row] = f2bf(vv.y);
        Vt[(c + 2) * TS + row] = f2bf(vv.z);
        Vt[(c + 3) * TS + row] = f2bf(vv.w);
    }
    // St^T: straight bf16 copy (already transposed in ws)
#pragma unroll
    for (int r = 0; r < 2; ++r) {
        const int idx = t + 256 * r;              // 0..511
        const int m = idx >> 3, dg = (idx & 7) * 8;
        *(short8*)&St[m * TS + dg] = *(const short8*)(Spb + m * D_ + dg);
    }
    __syncthreads();

    const int w = t >> 6, lane = t & 63;
    const int row16 = lane & 15, quad = lane >> 4;

    // ---- QK^T: wave w -> rows 16w..16w+15, all 4 col-tiles ----------------
    short8 aq[2];
#pragma unroll
    for (int kt = 0; kt < 2; ++kt)
        aq[kt] = *(const short8*)&Qb[(16 * w + row16) * TS + quad * 8 + 32 * kt];

    f32x4 accA[4] = {f32x4{0,0,0,0}, f32x4{0,0,0,0}, f32x4{0,0,0,0}, f32x4{0,0,0,0}};
#pragma unroll
    for (int kt = 0; kt < 2; ++kt)
#pragma unroll
        for (int c = 0; c < 4; ++c) {
            const short8 b = *(const short8*)&Kb[(16 * c + row16) * TS + quad * 8 + 32 * kt];
            accA[c] = __builtin_amdgcn_mfma_f32_16x16x32_bf16(aq[kt], b, accA[c], 0, 0, 0);
        }

    // ---- mask (causal) in fp32 + rowsums ----------------------------------
    float rs[4] = {0.f, 0.f, 0.f, 0.f};
#pragma unroll
    for (int c = 0; c < 4; ++c)
#pragma unroll
        for (int r = 0; r < 4; ++r) {
            const int row = 16 * w + quad * 4 + r;
            const int col = 16 * c + row16;
            const float v = (col <= row) ? accA[c][r] : 0.f;
            accA[c][r] = v;
            rs[r] += v;
        }
#pragma unroll
    for (int off = 1; off < 16; off <<= 1)
#pragma unroll
        for (int r = 0; r < 4; ++r)
            rs[r] += __shfl_xor(rs[r], off, 64);
    if (row16 == 0) {
#pragma unroll
        for (int r = 0; r < 4; ++r)
            Rs[16 * w + quad * 4 + r] = rs[r];
    }
    __syncthreads();   // all Kb reads done; Rs complete

    // ---- write A (bf16) into Kb slab; compute Z ---------------------------
#pragma unroll
    for (int c = 0; c < 4; ++c)
#pragma unroll
        for (int r = 0; r < 4; ++r)
            Kb[(16 * w + quad * 4 + r) * TS + 16 * c + row16] = f2bf(accA[c][r]);

    if (t < C) {
        float zd = 0.f;
#pragma unroll 8
        for (int d = 0; d < D_; ++d)
            zd += bf2f(Qb[t * TS + d]) * kpref[d];
        Zs[t] = 1.0f / (zd + Rs[t] + EPS_);
    }
    __syncthreads();   // Ab + Zs ready

    // ---- out = (A @ V + Q @ Sp) * Z ---------------------------------------
    f32x4 accO[4] = {f32x4{0,0,0,0}, f32x4{0,0,0,0}, f32x4{0,0,0,0}, f32x4{0,0,0,0}};
#pragma unroll
    for (int kt = 0; kt < 2; ++kt) {
        const short8 aA = *(const short8*)&Kb[(16 * w + row16) * TS + quad * 8 + 32 * kt];
#pragma unroll
        for (int c = 0; c < 4; ++c) {
            const short8 bV = *(const short8*)&Vt[(16 * c + row16) * TS + quad * 8 + 32 * kt];
            accO[c] = __builtin_amdgcn_mfma_f32_16x16x32_bf16(aA, bV, accO[c], 0, 0, 0);
        }
#pragma unroll
        for (int c = 0; c < 4; ++c) {
            const short8 bS = *(const short8*)&St[(16 * c + row16) * TS + quad * 8 + 32 * kt];
            accO[c] = __builtin_amdgcn_mfma_f32_16x16x32_bf16(aq[kt], bS, accO[c], 0, 0, 0);
        }
    }

#pragma unroll
    for (int r = 0; r < 4; ++r) {
        const int row = 16 * w + quad * 4 + r;
        const float z = Zs[row];
        const size_t ob = ((size_t)(n * L_ + g * C + row) * H_ + h) * M_;
#pragma unroll
        for (int c = 0; c < 4; ++c)
            out[ob + 16 * c + row16] = accO[c][r] * z;
    }
}

extern "C" void kernel_launch(void* const* d_in, const int* in_sizes, int n_in,
                              void* d_out, int out_size, void* d_ws, size_t ws_size,
                              hipStream_t stream) {
    const float* q = (const float*)d_in[0];
    const float* k = (const float*)d_in[1];
    const float* v = (const float*)d_in[2];
    float* out = (float*)d_out;
    unsigned short* wsSb = (unsigned short*)d_ws;            // NH*G*D*M bf16 (4 MB)
    float* wsK = (float*)((char*)d_ws + (size_t)NH * G * D_ * M_ * 2);  // fp32 128 KB

    k_chunksum<<<dim3(NH * G), dim3(256), 0, stream>>>(k, v, wsSb, wsK);
    k_scan<<<dim3(NH * 8), dim3(256), 0, stream>>>(wsSb, wsK);
    k_out<<<dim3(NH * G), dim3(256), 0, stream>>>(q, k, v, out, wsSb, wsK);
}